// Round 1
// baseline (78.319 us; speedup 1.0000x reference)
//
#include <hip/hip_runtime.h>

// Voxel merge (2x2x2, blocks ordered i*4+j*2+k) + mask + LayerNorm(768) + GEMM [65536,768]x[768,192].
// B=2, D=H=W=64, C=96 -> merged M=65536 rows of 768 ch; out 192 ch + mask_out.
#define C8   768
#define NOUT 192
#define M_TOTAL 65536
#define OUT0 (M_TOTAL * NOUT)   // 12582912; mask_out follows

typedef __attribute__((ext_vector_type(8))) short  short8;   // 8 x bf16 MFMA fragment
typedef __attribute__((ext_vector_type(4))) float  f32x4;    // MFMA accumulator
typedef __attribute__((ext_vector_type(4))) unsigned short us4;

__device__ __forceinline__ unsigned short f2bf(float f) {
    union { float f; unsigned u; } a; a.f = f;
    unsigned r = a.u + 0x7FFFu + ((a.u >> 16) & 1u);  // round-to-nearest-even
    return (unsigned short)(r >> 16);
}

// Pre-pack W [768][192] fp32 -> bf16 in per-lane MFMA B-fragment order:
// Wb[((ks*12 + fn)*64 + l)*8 + e] = bf16(W[(ks*32 + (l>>4)*8 + e)*192 + fn*16 + (l&15)])
__global__ __launch_bounds__(256) void prepw_kernel(const float* __restrict__ Wm,
                                                    unsigned short* __restrict__ Wb) {
    int t = blockIdx.x * 256 + threadIdx.x;
    if (t >= 24 * 12 * 512) return;
    int e  = t & 7;
    int l  = (t >> 3) & 63;
    int f  = t >> 9;          // ks*12 + fn
    int fn = f % 12;
    int ks = f / 12;
    int k = ks * 32 + ((l >> 4) << 3) + e;
    int n = fn * 16 + (l & 15);
    Wb[t] = f2bf(Wm[k * NOUT + n]);
}

__global__ __launch_bounds__(256) void fused_kernel(
    const float* __restrict__ x, const float* __restrict__ mask,
    const float* __restrict__ gamma, const float* __restrict__ beta,
    const unsigned short* __restrict__ Wb, float* __restrict__ out)
{
    // A tile: 32 rows x 768 bf16, row-major (stride 1536B), XOR-swizzled by ((row&7)<<4)
    // to break the 16-way bank conflict (1536 % 128 == 0).
    __shared__ unsigned short Alds[32 * 768];   // 48 KiB
    const int tid = threadIdx.x;
    const int l   = tid & 63;
    const int wv  = tid >> 6;
    const int rowbase = blockIdx.x * 32;

    // ---------------- Phase 1: gather + mask + LayerNorm -> LDS bf16 ----------------
    for (int i = 0; i < 8; ++i) {
        const int r  = (wv << 3) + i;          // each wave owns 8 rows
        const int rg = rowbase + r;
        const int w2 = rg & 31, h2 = (rg >> 5) & 31, d2 = (rg >> 10) & 31, b = rg >> 15;
        const int vbase = ((b * 64 + d2 * 2) * 64 + h2 * 2) * 64 + w2 * 2; // mask-space idx

        float vs[12];
        float s = 0.f, s2 = 0.f;
#pragma unroll
        for (int m = 0; m < 3; ++m) {
            const int c8 = (m << 8) + (l << 2);          // merged channel (x4)
            const int bi = c8 / 96;                      // sub-voxel block (i*4+j*2+k)
            const int ch = c8 - bi * 96;
            const int voff = vbase + ((bi >> 2) * 64 + ((bi >> 1) & 1)) * 64 + (bi & 1);
            const float4 v = *(const float4*)(x + (size_t)voff * 96 + ch);
            const float mv = mask[voff];
            const float a0 = v.x * mv, a1 = v.y * mv, a2 = v.z * mv, a3 = v.w * mv;
            vs[m * 4 + 0] = a0; vs[m * 4 + 1] = a1; vs[m * 4 + 2] = a2; vs[m * 4 + 3] = a3;
            s  += (a0 + a1) + (a2 + a3);
            s2 += (a0 * a0 + a1 * a1) + (a2 * a2 + a3 * a3);
        }
#pragma unroll
        for (int off = 32; off >= 1; off >>= 1) {   // 64-lane butterfly reduce
            s  += __shfl_xor(s,  off);
            s2 += __shfl_xor(s2, off);
        }
        const float mu  = s * (1.f / 768.f);
        const float var = s2 * (1.f / 768.f) - mu * mu;   // biased variance
        const float rs  = rsqrtf(var + 1e-5f);
        const int swz = (r & 7) << 4;
        char* rowp = (char*)Alds + r * 1536;
#pragma unroll
        for (int m = 0; m < 3; ++m) {
            const int c8 = (m << 8) + (l << 2);
            const float4 g  = *(const float4*)(gamma + c8);
            const float4 bt = *(const float4*)(beta  + c8);
            us4 o;
            o.x = f2bf((vs[m * 4 + 0] - mu) * rs * g.x + bt.x);
            o.y = f2bf((vs[m * 4 + 1] - mu) * rs * g.y + bt.y);
            o.z = f2bf((vs[m * 4 + 2] - mu) * rs * g.z + bt.z);
            o.w = f2bf((vs[m * 4 + 3] - mu) * rs * g.w + bt.w);
            *(us4*)(rowp + ((c8 << 1) ^ swz)) = o;   // 8B store, wave-linear -> no conflict
        }
        if (l == 0) {   // mask_out = (sum of 8 merged mask vals) > 0
            float ms = 0.f;
#pragma unroll
            for (int bi = 0; bi < 8; ++bi)
                ms += mask[vbase + ((bi >> 2) * 64 + ((bi >> 1) & 1)) * 64 + (bi & 1)];
            out[OUT0 + rg] = (ms > 0.f) ? 1.0f : 0.0f;
        }
    }
    __syncthreads();

    // ---------------- Phase 2: [32 x 192] = A[32x768] * W[768x192] via MFMA ----------------
    // wave wv owns cols [wv*48, wv*48+48) = 3 col-fragments; rows: 2 row-fragments.
    f32x4 acc[2][3] = {};
    const int lrow = l & 15;
    const int kq   = (l >> 4) << 4;        // byte offset of this lane's k-chunk
    const int swz2 = (l & 7) << 4;         // row-swizzle: (row&7) == (l&7) for both frags
    const char* aBase = (const char*)Alds + lrow * 1536;
    const short8* Wv = (const short8*)Wb;
    const int bbase = wv * 3 * 64 + l;

#pragma unroll 2
    for (int ks = 0; ks < 24; ++ks) {
        const int ko = ((ks << 6) + kq) ^ swz2;
        short8 a0 = *(const short8*)(aBase + ko);
        short8 a1 = *(const short8*)(aBase + 16 * 1536 + ko);
        short8 b0 = Wv[ks * 768 + bbase];
        short8 b1 = Wv[ks * 768 + bbase + 64];
        short8 b2 = Wv[ks * 768 + bbase + 128];
        acc[0][0] = __builtin_amdgcn_mfma_f32_16x16x32_bf16(a0, b0, acc[0][0], 0, 0, 0);
        acc[1][0] = __builtin_amdgcn_mfma_f32_16x16x32_bf16(a1, b0, acc[1][0], 0, 0, 0);
        acc[0][1] = __builtin_amdgcn_mfma_f32_16x16x32_bf16(a0, b1, acc[0][1], 0, 0, 0);
        acc[1][1] = __builtin_amdgcn_mfma_f32_16x16x32_bf16(a1, b1, acc[1][1], 0, 0, 0);
        acc[0][2] = __builtin_amdgcn_mfma_f32_16x16x32_bf16(a0, b2, acc[0][2], 0, 0, 0);
        acc[1][2] = __builtin_amdgcn_mfma_f32_16x16x32_bf16(a1, b2, acc[1][2], 0, 0, 0);
    }

    // C/D layout: col = lane&15, row = (lane>>4)*4 + j  (m89-verified)
    const int colb = wv * 48 + lrow;
    const int r0   = rowbase + ((l >> 4) << 2);
#pragma unroll
    for (int fm = 0; fm < 2; ++fm)
#pragma unroll
        for (int fn = 0; fn < 3; ++fn)
#pragma unroll
            for (int j = 0; j < 4; ++j)
                out[(size_t)(r0 + fm * 16 + j) * NOUT + colb + fn * 16] = acc[fm][fn][j];
}

extern "C" void kernel_launch(void* const* d_in, const int* in_sizes, int n_in,
                              void* d_out, int out_size, void* d_ws, size_t ws_size,
                              hipStream_t stream) {
    const float* x     = (const float*)d_in[0];
    const float* mask  = (const float*)d_in[1];
    const float* gamma = (const float*)d_in[2];
    const float* beta  = (const float*)d_in[3];
    const float* Wm    = (const float*)d_in[4];
    float* out = (float*)d_out;
    unsigned short* Wb = (unsigned short*)d_ws;   // 294912 B of scratch

    prepw_kernel<<<576, 256, 0, stream>>>(Wm, Wb);
    fused_kernel<<<2048, 256, 0, stream>>>(x, mask, gamma, beta, Wb, out);
}